// Round 1
// baseline (1380.126 us; speedup 1.0000x reference)
//
#include <hip/hip_runtime.h>

// B=4, H=16, S=2048, D=64. fp32 in; out = [context (B,H,S,D) | attn (B,H,S,S)] fp32.
// Strategy: bf16 MFMA 16x16x32. Per block: 128 q-rows, loop 32 iters of 64 keys.
// S^T = K * (Q/8)^T so C-layout regs hold 4 consecutive keys -> float4 attn stores
// and packed ds_write_b64 into Pb. V staged transposed in LDS for PV B-frags.

typedef __attribute__((ext_vector_type(4))) float f32x4;
typedef __attribute__((ext_vector_type(8))) short bf16x8;
typedef __attribute__((ext_vector_type(4))) short bf16x4;

#define S_LEN 2048
#define D_HEAD 64
#define KST 72  // LDS row stride in shorts (64 + 8 pad, keeps 16B row alignment, 2-way-free)

__device__ __forceinline__ short f2bf(float x) {
  union { float f; unsigned u; } v; v.f = x;
  unsigned r = v.u + 0x7fffu + ((v.u >> 16) & 1u);  // RNE to bf16
  return (short)(r >> 16);
}

__device__ __forceinline__ bf16x8 cvt8(f32x4 a, f32x4 b) {
  bf16x8 r;
  r[0] = f2bf(a[0]); r[1] = f2bf(a[1]); r[2] = f2bf(a[2]); r[3] = f2bf(a[3]);
  r[4] = f2bf(b[0]); r[5] = f2bf(b[1]); r[6] = f2bf(b[2]); r[7] = f2bf(b[3]);
  return r;
}

__global__ void ScaledDotProductAttention_40166534152796_kernel(
    const float* __restrict__ Q, const float* __restrict__ K,
    const float* __restrict__ V, float* __restrict__ ctx,
    float* __restrict__ attn) {
  __shared__ short Kb[64 * KST];   // K tile, row-major [key][d]
  __shared__ short Vt[64 * KST];   // V tile, transposed [d][key]
  __shared__ short Pb[128 * KST];  // relu'd P tile bf16 [q_local][key_local]

  const int tid = threadIdx.x;
  const int wave = tid >> 6;
  const int lane = tid & 63;
  const int t = lane & 15;     // n-index within 16-tile
  const int quad = lane >> 4;  // 0..3

  const int qblk = blockIdx.x;  // 0..15
  const int bh = blockIdx.y;    // 0..63

  const float* Qh = Q + (size_t)bh * S_LEN * D_HEAD;
  const float* Kh = K + (size_t)bh * S_LEN * D_HEAD;
  const float* Vh = V + (size_t)bh * S_LEN * D_HEAD;
  float* ctxh = ctx + (size_t)bh * S_LEN * D_HEAD;
  float* attnh = attn + (size_t)bh * S_LEN * S_LEN;

  // ---- Q B-fragments (scaled by 1/8), loaded once, kept in regs ----
  // B[k=d][n=q]: lane n = t -> q row; element j -> d = s*32 + quad*8 + j
  bf16x8 qfrag[2][2];
#pragma unroll
  for (int qc = 0; qc < 2; ++qc) {
#pragma unroll
    for (int s = 0; s < 2; ++s) {
      const int qrow = qblk * 128 + wave * 32 + qc * 16 + t;
      const f32x4* p = (const f32x4*)(Qh + qrow * D_HEAD + s * 32 + quad * 8);
      f32x4 a = p[0], b = p[1];
      a *= 0.125f; b *= 0.125f;
      qfrag[qc][s] = cvt8(a, b);
    }
  }

  // staging assignment: 4 threads per row, 16 d-elements each
  const int srow = tid >> 2;          // 0..63 (key row of tile)
  const int dseg = (tid & 3) * 16;    // 0,16,32,48

  f32x4 acc_c[2][4];
#pragma unroll
  for (int r = 0; r < 2; ++r)
#pragma unroll
    for (int c = 0; c < 4; ++c) acc_c[r][c] = (f32x4)(0.0f);

  for (int kt = 0; kt < 32; ++kt) {
    __syncthreads();  // previous iter's Kb/Vt reads done

    // ---- stage K tile (row-major bf16) and V tile (transposed bf16) ----
    {
      const f32x4* kp = (const f32x4*)(Kh + (size_t)(kt * 64 + srow) * D_HEAD + dseg);
      f32x4 k0 = kp[0], k1 = kp[1], k2 = kp[2], k3 = kp[3];
      *(bf16x8*)&Kb[srow * KST + dseg] = cvt8(k0, k1);
      *(bf16x8*)&Kb[srow * KST + dseg + 8] = cvt8(k2, k3);

      const f32x4* vp = (const f32x4*)(Vh + (size_t)(kt * 64 + srow) * D_HEAD + dseg);
      f32x4 v0 = vp[0], v1 = vp[1], v2 = vp[2], v3 = vp[3];
      float vv[16];
#pragma unroll
      for (int j = 0; j < 4; ++j) { vv[j] = v0[j]; vv[4 + j] = v1[j]; vv[8 + j] = v2[j]; vv[12 + j] = v3[j]; }
#pragma unroll
      for (int j = 0; j < 16; ++j) Vt[(dseg + j) * KST + srow] = f2bf(vv[j]);
    }
    __syncthreads();

    // ---- QK^T: S^T tile [64 keys x 32 q] per wave ----
    // A = K: A[m=key][k=d], lane m = t -> key row kr*16+t, elem j -> d = s*32+quad*8+j
    bf16x8 afr[4][2];
#pragma unroll
    for (int kr = 0; kr < 4; ++kr)
#pragma unroll
      for (int s = 0; s < 2; ++s)
        afr[kr][s] = *(const bf16x8*)&Kb[(kr * 16 + t) * KST + s * 32 + quad * 8];

    f32x4 sa[4][2];
#pragma unroll
    for (int kr = 0; kr < 4; ++kr)
#pragma unroll
      for (int qc = 0; qc < 2; ++qc) sa[kr][qc] = (f32x4)(0.0f);

#pragma unroll
    for (int s = 0; s < 2; ++s)
#pragma unroll
      for (int kr = 0; kr < 4; ++kr)
#pragma unroll
        for (int qc = 0; qc < 2; ++qc)
          sa[kr][qc] = __builtin_amdgcn_mfma_f32_16x16x32_bf16(
              afr[kr][s], qfrag[qc][s], sa[kr][qc], 0, 0, 0);

    // ---- relu, store attn (float4, 4 consecutive keys/lane), write Pb ----
#pragma unroll
    for (int kr = 0; kr < 4; ++kr) {
#pragma unroll
      for (int qc = 0; qc < 2; ++qc) {
        f32x4 v = sa[kr][qc];
#pragma unroll
        for (int i = 0; i < 4; ++i) v[i] = fmaxf(v[i], 0.0f);
        const int qg = qblk * 128 + wave * 32 + qc * 16 + t;
        const int key = kt * 64 + kr * 16 + quad * 4;
        *(f32x4*)(attnh + (size_t)qg * S_LEN + key) = v;
        bf16x4 pv;
#pragma unroll
        for (int i = 0; i < 4; ++i) pv[i] = f2bf(v[i]);
        *(bf16x4*)&Pb[(wave * 32 + qc * 16 + t) * KST + kr * 16 + quad * 4] = pv;
      }
    }

    // ---- PV: ctx[q][d] += P[q][key] * V[key][d] ----
    // A = P from Pb (row-contig); B = V^T from Vt (row-contig)
#pragma unroll
    for (int s2 = 0; s2 < 2; ++s2) {
      bf16x8 pa[2], vb[4];
#pragma unroll
      for (int r = 0; r < 2; ++r)
        pa[r] = *(const bf16x8*)&Pb[(wave * 32 + r * 16 + t) * KST + s2 * 32 + quad * 8];
#pragma unroll
      for (int c = 0; c < 4; ++c)
        vb[c] = *(const bf16x8*)&Vt[(c * 16 + t) * KST + s2 * 32 + quad * 8];
#pragma unroll
      for (int r = 0; r < 2; ++r)
#pragma unroll
        for (int c = 0; c < 4; ++c)
          acc_c[r][c] = __builtin_amdgcn_mfma_f32_16x16x32_bf16(
              pa[r], vb[c], acc_c[r][c], 0, 0, 0);
    }
  }

  // ---- store context: C layout row=quad*4+i -> q, col=t -> d ----
#pragma unroll
  for (int r = 0; r < 2; ++r) {
#pragma unroll
    for (int c = 0; c < 4; ++c) {
#pragma unroll
      for (int i = 0; i < 4; ++i) {
        const int qg = qblk * 128 + wave * 32 + r * 16 + quad * 4 + i;
        const int d = c * 16 + t;
        ctxh[(size_t)qg * D_HEAD + d] = acc_c[r][c][i];
      }
    }
  }
}

extern "C" void kernel_launch(void* const* d_in, const int* in_sizes, int n_in,
                              void* d_out, int out_size, void* d_ws, size_t ws_size,
                              hipStream_t stream) {
  const float* Q = (const float*)d_in[0];
  const float* K = (const float*)d_in[1];
  const float* V = (const float*)d_in[2];
  float* ctx = (float*)d_out;
  float* attn = (float*)d_out + (size_t)4 * 16 * 2048 * 64;  // after context

  dim3 grid(16, 64, 1);   // (S/128, B*H)
  dim3 block(256, 1, 1);  // 4 waves
  ScaledDotProductAttention_40166534152796_kernel<<<grid, block, 0, stream>>>(
      Q, K, V, ctx, attn);
}